// Round 15
// baseline (194.871 us; speedup 1.0000x reference)
//
#include <hip/hip_runtime.h>
#include <math.h>

#define HID    64
#define MSTEPS 60
#define NPTS   32
#define RPTSC  128
#define BTOT   (RPTSC*NPTS)    // 4096 paths
#define NSIM   (2*BTOT)        // 8192 path-branches
#define NWAVE  (NSIM/2)        // 4096 waves, 2 path-branches per wave

// hard-coded model constants (match reference, fp32 semantics)
#define C_DT     0.025f
#define C_SQDT   0.15811388300841897f   // sqrt(0.025)
#define C_ALPHA  0.8f
#define C_RHO    0.3f
#define C_SQ1MR2 0.9539392014169456f    // sqrt(1-0.09)
#define C_KAPPA  1.2f
#define C_R      0.02f
#define C_SIGMA  0.2f
#define C_SIGY   0.3f
#define C_LBW    1e-3f
#define C_LOGLBW -6.907755279f          // log(1e-3)

// per-wave LDS layout:
//   [0,2304)      A-buffer: 16 rows x 144 B (64 f16 + 16 B pad)
//   [2304,4352)   DV: float4[2][64]
//   [4352,4864)   DA: float[2][64]
#define WAVE_LDS 4864
#define A_ROW    144
#define OFF_DV   2304
#define OFF_DA   4352

typedef _Float16 half8 __attribute__((ext_vector_type(8)));
typedef float    f32x4 __attribute__((ext_vector_type(4)));

__device__ __forceinline__ float rlanef(float v, int l) {
    return __int_as_float(__builtin_amdgcn_readlane(__float_as_int(v), l));
}
__device__ __forceinline__ float bperm(int addr, float v) {
    return __int_as_float(__builtin_amdgcn_ds_bpermute(addr, __float_as_int(v)));
}
__device__ __forceinline__ f32x4 MFMA(half8 a, half8 b, f32x4 c) {
    return __builtin_amdgcn_mfma_f32_16x16x32_f16(a, b, c, 0, 0, 0);
}
// tanh(x) = 1 - 2/(e^{2x}+1)
__device__ __forceinline__ float ftanh(float x) {
    float e = __expf(2.0f * x);
    return 1.0f - 2.0f * __builtin_amdgcn_rcpf(e + 1.0f);
}

// sim: per-branch derivatives stored directly (no atomics, no zero-init).
// sd[c*NSIM + branch], branch = simb*BTOT + pg; branch & 31 == eval point.
__global__ __launch_bounds__(256, 4) void sim_kernel(
    const float* __restrict__ noise,
    const float* __restrict__ w1, const float* __restrict__ b1,
    const float* __restrict__ w2, const float* __restrict__ b2,
    const float* __restrict__ w3, const float* __restrict__ b3,
    const float* __restrict__ Wp, const float* __restrict__ Yp,
    float* __restrict__ sd)
{
    __shared__ __align__(16) char smem[4 * WAVE_LDS];
    const int lane = threadIdx.x & 63;
    const int quad = lane >> 4;      // 0..3
    const int mrow = lane & 15;      // 0..15
    const int par  = lane & 1;       // which of the wave's 2 paths this lane works
    char* wb = smem + (threadIdx.x >> 6) * WAVE_LDS;

    const int w = __builtin_amdgcn_readfirstlane(
        (int)((blockIdx.x * blockDim.x + threadIdx.x) >> 6));   // 0..4095
    const int simb = w >> 11;                 // antithetic branch (uniform per wave)
    const int pg   = 2*(w & 2047) + par;      // per-lane global path 0..4095
    const int i    = pg & (NPTS - 1);         // per-lane eval point

    // bpermute source-lane addresses for policy-jet extraction (loop-invariant):
    // path p rows 8p..8p+3 live in quad 2p (lane 32p) regs x..w; row 8p+4 in
    // quad 2p+1 (lane 32p+16) reg x. addr = lane*4.
    const int addrA = par << 7;         // (par*32)*4
    const int addrB = addrA + 64;       // (+16)*4

    // per-lane layer-1 weights (lane = hidden unit)
    const float cW  = w1[lane];
    const float cT  = w1[HID + lane];
    const float cYw = w1[2*HID + lane];
    const float b1k = b1[lane];
    const float b2k = b2[lane];
    const float b3v = b3[0];
    const float cW2  = cW * cW;
    const float cWYc = cW * cYw;

    // MFMA B fragments (f16): B[k][n], n=mrow+t*16, k=q*32+quad*8+j
    half8 B00, B01, B02, B03, B10, B11, B12, B13, W30, W31;
    {
        half8 h;
        #define LOADB(dst, q, t) \
            { for (int j = 0; j < 8; ++j) \
                h[j] = (_Float16)w2[((q)*32 + quad*8 + j)*HID + (t)*16 + mrow]; \
              dst = h; }
        LOADB(B00, 0, 0) LOADB(B01, 0, 1) LOADB(B02, 0, 2) LOADB(B03, 0, 3)
        LOADB(B10, 1, 0) LOADB(B11, 1, 1) LOADB(B12, 1, 2) LOADB(B13, 1, 3)
        #undef LOADB
        for (int j = 0; j < 8; ++j) h[j] = (_Float16)w3[0*32 + quad*8 + j];
        W30 = h;
        for (int j = 0; j < 8; ++j) h[j] = (_Float16)w3[1*32 + quad*8 + j];
        W31 = h;
    }

    // zero A-buffer once (rows 5-7, 13-15 must stay zero)
    for (int off = lane*4; off < 16*A_ROW; off += 256)
        *(float*)(wb + off) = 0.0f;

    // LDS addresses
    _Float16* swp = (_Float16*)(wb + lane*2);   // + row*72 elements
    char* arp0 = wb + mrow*A_ROW + quad*16;     // A-frag k-iter 0 (+64 B for iter 1)

    // per-lane noise pointers
    const float* zp1 = noise + (size_t)(simb*2 + 0) * MSTEPS * BTOT + pg;
    const float* zp2 = noise + (size_t)(simb*2 + 1) * MSTEPS * BTOT + pg;

    // ---- precomputed dynamics coefficients (fold anti & constants)
    const float anti = simb ? -1.0f : 1.0f;
    const float ksa  = C_SIGMA * C_ALPHA;
    const float ks2  = C_SIGMA * C_SIGMA;
    const float ksn  = anti * C_SIGMA * C_SQDT;
    const float kFy  = ksa * C_DT;
    const float ksd  = ks2 * C_DT;
    const float kv   = 0.5f * ks2 * C_DT;
    const float kRdt = C_R * C_DT;
    const float ky1  = anti * C_SIGY * C_SQDT * C_RHO;
    const float ky2  = anti * C_SIGY * C_SQDT * C_SQ1MR2;
    const float cYfac = 1.0f - C_KAPPA * C_DT;

    // per-lane path state + jets of L = logW
    const float W0 = Wp[i];
    float L   = __logf(fmaxf(W0, C_LBW));
    float W   = __expf(L);
    float Yv  = Yp[i];
    float tmt = 1.5f;
    float gW  = 1.0f / W0;
    float hWW = -gW * gW;
    float gY  = 0.0f, hWY = 0.0f;
    float cYt = 1.0f;

    #pragma unroll 1
    for (int m = 0; m < MSTEPS; ++m) {
        asm volatile("" : "+v"(B00), "+v"(B01), "+v"(B02), "+v"(B03),
                          "+v"(B10), "+v"(B11), "+v"(B12), "+v"(B13),
                          "+v"(W30), "+v"(W31));

        const float z1 = zp1[(size_t)m * BTOT];
        const float z2 = zp2[(size_t)m * BTOT];

        const float Wb0 = rlanef(W, 0),  Wb1 = rlanef(W, 1);
        const float Yb0 = rlanef(Yv, 0), Yb1 = rlanef(Yv, 1);

        // ---- layer 1 + tanh for both paths; marshal A rows 8p..8p+4
        const float base1 = fmaf(tmt, cT, b1k);
        {
            const float t1 = ftanh(fmaf(Wb0, cW, fmaf(Yb0, cYw, base1)));
            const float dp = 1.0f - t1*t1, ddp = -2.0f*t1*dp;
            swp[0*72] = (_Float16)t1;
            swp[1*72] = (_Float16)(dp * cW);
            swp[2*72] = (_Float16)(dp * cYw);
            swp[3*72] = (_Float16)(ddp * cW2);
            swp[4*72] = (_Float16)(ddp * cWYc);
        }
        {
            const float t1 = ftanh(fmaf(Wb1, cW, fmaf(Yb1, cYw, base1)));
            const float dp = 1.0f - t1*t1, ddp = -2.0f*t1*dp;
            swp[8*72]  = (_Float16)t1;
            swp[9*72]  = (_Float16)(dp * cW);
            swp[10*72] = (_Float16)(dp * cYw);
            swp[11*72] = (_Float16)(ddp * cW2);
            swp[12*72] = (_Float16)(ddp * cWYc);
        }

        half8 af0 = __builtin_bit_cast(half8, *(const f32x4*)arp0);
        half8 af1 = __builtin_bit_cast(half8, *(const f32x4*)(arp0 + 64));

        // ---- layer 2 GEMM: 4 N-tiles x 2 K-iters
        f32x4 acc[4];
        const f32x4 zz = {0.f, 0.f, 0.f, 0.f};
        acc[0] = MFMA(af1, B10, MFMA(af0, B00, zz));
        acc[1] = MFMA(af1, B11, MFMA(af0, B01, zz));
        acc[2] = MFMA(af1, B12, MFMA(af0, B02, zz));
        acc[3] = MFMA(af1, B13, MFMA(af0, B03, zz));

        // ---- D transpose via LDS
        {
            const int p = quad >> 1;
            if (!(quad & 1)) {
                #pragma unroll
                for (int t = 0; t < 4; ++t)
                    *(f32x4*)(wb + OFF_DV + (p*64 + t*16 + mrow)*16) = acc[t];
            } else {
                #pragma unroll
                for (int t = 0; t < 4; ++t)
                    *(float*)(wb + OFF_DA + (p*64 + t*16 + mrow)*4) = acc[t].x;
            }
        }

        // ---- per-lane (unit k) read both paths' activations, compute h rows
        const f32x4 av0 = *(const f32x4*)(wb + OFF_DV + lane*16);
        const f32x4 av1 = *(const f32x4*)(wb + OFF_DV + (64 + lane)*16);
        const float awy0 = *(const float*)(wb + OFF_DA + lane*4);
        const float awy1 = *(const float*)(wb + OFF_DA + (64 + lane)*4);
        {
            const float t2 = ftanh(av0.x + b2k);
            const float d2 = 1.0f - t2*t2, dd2 = -2.0f*t2*d2;
            const float q  = dd2 * av0.y;
            swp[0*72] = (_Float16)t2;
            swp[1*72] = (_Float16)(d2 * av0.y);
            swp[2*72] = (_Float16)(d2 * av0.z);
            swp[3*72] = (_Float16)fmaf(q, av0.y, d2 * av0.w);
            swp[4*72] = (_Float16)fmaf(q, av0.z, d2 * awy0);
        }
        {
            const float t2 = ftanh(av1.x + b2k);
            const float d2 = 1.0f - t2*t2, dd2 = -2.0f*t2*d2;
            const float q  = dd2 * av1.y;
            swp[8*72]  = (_Float16)t2;
            swp[9*72]  = (_Float16)(d2 * av1.y);
            swp[10*72] = (_Float16)(d2 * av1.z);
            swp[11*72] = (_Float16)fmaf(q, av1.y, d2 * av1.w);
            swp[12*72] = (_Float16)fmaf(q, av1.z, d2 * awy1);
        }

        // ---- layer 3 via MFMA (w3 broadcast over n -> all cols equal)
        half8 bf0 = __builtin_bit_cast(half8, *(const f32x4*)arp0);
        half8 bf1 = __builtin_bit_cast(half8, *(const f32x4*)(arp0 + 64));
        f32x4 acc4 = MFMA(bf1, W31, MFMA(bf0, W30, zz));

        // ---- extract policy jets via ds_bpermute (no LDS round trip):
        // pull rows 8p..8p+3 from lane 32*par (regs x..w), row 8p+4 from 32*par+16
        const float pi  = bperm(addrA, acc4.x) + b3v;
        const float pW  = bperm(addrA, acc4.y);
        const float pY  = bperm(addrA, acc4.z);
        const float pWW = bperm(addrA, acc4.w);
        const float pWY = bperm(addrB, acc4.x);

        // ---- dynamics + jet update (refactored: shared GdtSn factor)
        const float Sn    = ksn * z1;
        const float say   = ksa * Yv;
        const float G     = fmaf(-ks2, pi, say);
        const float GdtSn = fmaf(G, C_DT, Sn);

        const float w2v  = W * W;
        const float piL  = pW * W;
        const float piLL = fmaf(pWW, w2v, piL);
        const float piY  = pY;
        const float piLY = pWY * W;

        const float pi2  = pi * pi;
        const float Lnew = fmaf(pi, fmaf(say, C_DT, Sn),
                                fmaf(-kv, pi2, L + kRdt));

        const float F_L  = fmaf(piL, GdtSn, 1.0f);
        const float F_Y  = fmaf(piY, GdtSn, kFy * pi);
        const float piL2 = piL * piL;
        const float F_LL = fmaf(piLL, GdtSn, -(ksd * piL2));
        const float F_LY = fmaf(piLY, GdtSn, piL * fmaf(-ksd, piY, kFy));

        const float gW2  = gW * gW;
        const float hWWn = fmaf(F_LL, gW2, F_L * hWW);
        const float hWYn = fmaf(F_LL, gW * gY,
                                fmaf(F_LY, gW * cYt, F_L * hWY));
        const float gWn  = F_L * gW;
        const float gYn  = fmaf(F_Y, cYt, F_L * gY);

        Yv  = fmaf(ky2, z2, fmaf(ky1, z1, cYfac * Yv));
        cYt *= cYfac;

        const float We   = __expf(Lnew);
        const bool  clip = (We < C_LBW);
        L   = clip ? C_LOGLBW : Lnew;
        W   = clip ? C_LBW    : We;
        gW  = clip ? 0.0f : gWn;
        gY  = clip ? 0.0f : gYn;
        hWW = clip ? 0.0f : hWWn;
        hWY = clip ? 0.0f : hWYn;
        tmt -= C_DT;
    }

    // terminal utility U = -0.25*exp(-4L); direct per-branch store (no atomics)
    const float E   = __expf(-4.0f * L);
    const float d1  = E * gW;
    const float d2v = fmaf(-4.0f * E, gW * gW, E * hWW);
    const float d3v = fmaf(-4.0f * E, gW * gY, E * hWY);

    if (lane < 2) {   // lane 0 = path 2w', lane 1 = path 2w'+1
        const int branch = simb * BTOT + pg;      // 0..8191, branch&31 == i
        sd[         branch] = 0.5f * d1;
        sd[  NSIM + branch] = 0.5f * d2v;
        sd[2*NSIM + branch] = 0.5f * d3v;
    }
}

__global__ void proj_kernel(const float* __restrict__ sd,
                            const float* __restrict__ Wp,
                            const float* __restrict__ Yp,
                            float* __restrict__ out)
{
    const int i = threadIdx.x;
    if (i >= NPTS) return;
    float lam = 0.0f, dW = 0.0f, dY = 0.0f;
    #pragma unroll 8
    for (int j = 0; j < NSIM / NPTS; ++j) {     // 256 entries, stride 32 (coalesced)
        const int idx = i + (j << 5);
        lam += sd[idx];
        dW  += sd[NSIM + idx];
        dY  += sd[2*NSIM + idx];
    }
    lam *= (1.0f / 2097152.0f);     // /128^3
    dW  *= (1.0f / 268435456.0f);   // /128^4
    dY  *= (1.0f / 268435456.0f);
    const float Wv = Wp[i], Yv = Yp[i];
    const float mmr   = C_SIGMA * (C_ALPHA * Yv);
    const float sig2  = C_SIGMA * C_SIGMA;
    const float coeff = -1.0f / (Wv * dW + 1e-8f);
    const float myo   = coeff * (lam * (mmr / sig2));
    const float hedge = coeff * (C_SIGMA * C_RHO * C_SIGY * dY / sig2);
    float v = myo + hedge;
    v = fminf(fmaxf(v, -2.0f), 2.0f);
    out[i] = v;
}

extern "C" void kernel_launch(void* const* d_in, const int* in_sizes, int n_in,
                              void* d_out, int out_size, void* d_ws, size_t ws_size,
                              hipStream_t stream) {
    const float* Wp    = (const float*)d_in[0];
    // d_in[1] = TmT (unused: reference simulates from T_H constant)
    const float* Yp    = (const float*)d_in[2];
    const float* noise = (const float*)d_in[3];
    const float* w1    = (const float*)d_in[4];
    const float* b1    = (const float*)d_in[5];
    const float* w2    = (const float*)d_in[6];
    const float* b2    = (const float*)d_in[7];
    const float* w3    = (const float*)d_in[8];
    const float* b3    = (const float*)d_in[9];
    float* out = (float*)d_out;
    float* sd  = (float*)d_ws;   // 3*8192 floats = 96 KB staging

    hipLaunchKernelGGL(sim_kernel, dim3(NWAVE/4), dim3(256), 0, stream,
                       noise, w1, b1, w2, b2, w3, b3, Wp, Yp, sd);
    hipLaunchKernelGGL(proj_kernel, dim3(1), dim3(64), 0, stream, sd, Wp, Yp, out);
}

// Round 16
// 188.426 us; speedup vs baseline: 1.0342x; 1.0342x over previous
//
#include <hip/hip_runtime.h>
#include <math.h>

#define HID    64
#define MSTEPS 60
#define NPTS   32
#define RPTSC  128
#define BTOT   (RPTSC*NPTS)    // 4096 paths
#define NSIM   (2*BTOT)        // 8192 path-branches
#define NWAVE  (NSIM/2)        // 4096 waves, 2 path-branches per wave

// hard-coded model constants (match reference, fp32 semantics)
#define C_DT     0.025f
#define C_SQDT   0.15811388300841897f   // sqrt(0.025)
#define C_ALPHA  0.8f
#define C_RHO    0.3f
#define C_SQ1MR2 0.9539392014169456f    // sqrt(1-0.09)
#define C_KAPPA  1.2f
#define C_R      0.02f
#define C_SIGMA  0.2f
#define C_SIGY   0.3f
#define C_LBW    1e-3f
#define C_LOGLBW -6.907755279f          // log(1e-3)

// per-wave LDS layout (f16 D-transpose: half the DS bytes of R14):
//   [0,2304)      A-buffer: 16 rows x 144 B (64 f16 + 16 B pad)
//   [2304,3328)   DV: f16x4[2][64]  (a0,aW,aY,aWW per path per unit, 8 B each)
//   [3328,3584)   DA: f16[2][64]    (aWY)
//   [3584,3616)   PV: float4[2]     (pi,pW,pY,pWW per path — f32, error-sensitive)
//   [3616,3624)   PA: float[2]      (pWY)
#define WAVE_LDS 3648
#define A_ROW    144
#define OFF_DV   2304
#define OFF_DA   3328
#define OFF_PV   3584
#define OFF_PA   3616

typedef _Float16 half8 __attribute__((ext_vector_type(8)));
typedef float    f32x4 __attribute__((ext_vector_type(4)));
typedef __fp16   fp16x2 __attribute__((ext_vector_type(2)));

__device__ __forceinline__ float rlanef(float v, int l) {
    return __int_as_float(__builtin_amdgcn_readlane(__float_as_int(v), l));
}
__device__ __forceinline__ f32x4 MFMA(half8 a, half8 b, f32x4 c) {
    return __builtin_amdgcn_mfma_f32_16x16x32_f16(a, b, c, 0, 0, 0);
}
// tanh(x) = 1 - 2/(e^{2x}+1)
__device__ __forceinline__ float ftanh(float x) {
    float e = __expf(2.0f * x);
    return 1.0f - 2.0f * __builtin_amdgcn_rcpf(e + 1.0f);
}
// pack two f32 -> f16x2 (RTZ) as int
__device__ __forceinline__ int pk16(float a, float b) {
    return __builtin_bit_cast(int, __builtin_amdgcn_cvt_pkrtz(a, b));
}

// sim: per-branch derivatives stored directly (no atomics, no zero-init).
// sd[c*NSIM + branch], branch = simb*BTOT + pg; branch & 31 == eval point.
__global__ __launch_bounds__(256, 4) void sim_kernel(
    const float* __restrict__ noise,
    const float* __restrict__ w1, const float* __restrict__ b1,
    const float* __restrict__ w2, const float* __restrict__ b2,
    const float* __restrict__ w3, const float* __restrict__ b3,
    const float* __restrict__ Wp, const float* __restrict__ Yp,
    float* __restrict__ sd)
{
    __shared__ __align__(16) char smem[4 * WAVE_LDS];
    const int lane = threadIdx.x & 63;
    const int quad = lane >> 4;      // 0..3
    const int mrow = lane & 15;      // 0..15
    const int par  = lane & 1;       // which of the wave's 2 paths this lane works
    char* wb = smem + (threadIdx.x >> 6) * WAVE_LDS;

    const int w = __builtin_amdgcn_readfirstlane(
        (int)((blockIdx.x * blockDim.x + threadIdx.x) >> 6));   // 0..4095
    const int simb = w >> 11;                 // antithetic branch (uniform per wave)
    const int pg   = 2*(w & 2047) + par;      // per-lane global path 0..4095
    const int i    = pg & (NPTS - 1);         // per-lane eval point

    // per-lane layer-1 weights (lane = hidden unit)
    const float cW  = w1[lane];
    const float cT  = w1[HID + lane];
    const float cYw = w1[2*HID + lane];
    const float b1k = b1[lane];
    const float b2k = b2[lane];
    const float b3v = b3[0];
    const float cW2  = cW * cW;
    const float cWYc = cW * cYw;

    // MFMA B fragments (f16): B[k][n], n=mrow+t*16, k=q*32+quad*8+j
    half8 B00, B01, B02, B03, B10, B11, B12, B13, W30, W31;
    {
        half8 h;
        #define LOADB(dst, q, t) \
            { for (int j = 0; j < 8; ++j) \
                h[j] = (_Float16)w2[((q)*32 + quad*8 + j)*HID + (t)*16 + mrow]; \
              dst = h; }
        LOADB(B00, 0, 0) LOADB(B01, 0, 1) LOADB(B02, 0, 2) LOADB(B03, 0, 3)
        LOADB(B10, 1, 0) LOADB(B11, 1, 1) LOADB(B12, 1, 2) LOADB(B13, 1, 3)
        #undef LOADB
        for (int j = 0; j < 8; ++j) h[j] = (_Float16)w3[0*32 + quad*8 + j];
        W30 = h;
        for (int j = 0; j < 8; ++j) h[j] = (_Float16)w3[1*32 + quad*8 + j];
        W31 = h;
    }

    // zero A-buffer once (rows 5-7, 13-15 must stay zero)
    for (int off = lane*4; off < 16*A_ROW; off += 256)
        *(float*)(wb + off) = 0.0f;

    // LDS addresses
    _Float16* swp = (_Float16*)(wb + lane*2);   // + row*72 elements
    char* arp0 = wb + mrow*A_ROW + quad*16;     // A-frag k-iter 0 (+64 B for iter 1)

    // per-lane noise pointers
    const float* zp1 = noise + (size_t)(simb*2 + 0) * MSTEPS * BTOT + pg;
    const float* zp2 = noise + (size_t)(simb*2 + 1) * MSTEPS * BTOT + pg;

    // ---- precomputed dynamics coefficients (fold anti & constants)
    const float anti = simb ? -1.0f : 1.0f;
    const float ksa  = C_SIGMA * C_ALPHA;
    const float ks2  = C_SIGMA * C_SIGMA;
    const float ksn  = anti * C_SIGMA * C_SQDT;
    const float kFy  = ksa * C_DT;
    const float ksd  = ks2 * C_DT;
    const float kv   = 0.5f * ks2 * C_DT;
    const float kRdt = C_R * C_DT;
    const float ky1  = anti * C_SIGY * C_SQDT * C_RHO;
    const float ky2  = anti * C_SIGY * C_SQDT * C_SQ1MR2;
    const float cYfac = 1.0f - C_KAPPA * C_DT;

    // per-lane path state + jets of L = logW
    const float W0 = Wp[i];
    float L   = __logf(fmaxf(W0, C_LBW));
    float W   = __expf(L);
    float Yv  = Yp[i];
    float tmt = 1.5f;
    float gW  = 1.0f / W0;
    float hWW = -gW * gW;
    float gY  = 0.0f, hWY = 0.0f;
    float cYt = 1.0f;

    #pragma unroll 1
    for (int m = 0; m < MSTEPS; ++m) {
        asm volatile("" : "+v"(B00), "+v"(B01), "+v"(B02), "+v"(B03),
                          "+v"(B10), "+v"(B11), "+v"(B12), "+v"(B13),
                          "+v"(W30), "+v"(W31));

        const float z1 = zp1[(size_t)m * BTOT];
        const float z2 = zp2[(size_t)m * BTOT];

        const float Wb0 = rlanef(W, 0),  Wb1 = rlanef(W, 1);
        const float Yb0 = rlanef(Yv, 0), Yb1 = rlanef(Yv, 1);

        // ---- layer 1 + tanh for both paths; marshal A rows 8p..8p+4
        const float base1 = fmaf(tmt, cT, b1k);
        {
            const float t1 = ftanh(fmaf(Wb0, cW, fmaf(Yb0, cYw, base1)));
            const float dp = 1.0f - t1*t1, ddp = -2.0f*t1*dp;
            swp[0*72] = (_Float16)t1;
            swp[1*72] = (_Float16)(dp * cW);
            swp[2*72] = (_Float16)(dp * cYw);
            swp[3*72] = (_Float16)(ddp * cW2);
            swp[4*72] = (_Float16)(ddp * cWYc);
        }
        {
            const float t1 = ftanh(fmaf(Wb1, cW, fmaf(Yb1, cYw, base1)));
            const float dp = 1.0f - t1*t1, ddp = -2.0f*t1*dp;
            swp[8*72]  = (_Float16)t1;
            swp[9*72]  = (_Float16)(dp * cW);
            swp[10*72] = (_Float16)(dp * cYw);
            swp[11*72] = (_Float16)(ddp * cW2);
            swp[12*72] = (_Float16)(ddp * cWYc);
        }

        half8 af0 = __builtin_bit_cast(half8, *(const f32x4*)arp0);
        half8 af1 = __builtin_bit_cast(half8, *(const f32x4*)(arp0 + 64));

        // ---- layer 2 GEMM: 4 N-tiles x 2 K-iters
        f32x4 acc[4];
        const f32x4 zz = {0.f, 0.f, 0.f, 0.f};
        acc[0] = MFMA(af1, B10, MFMA(af0, B00, zz));
        acc[1] = MFMA(af1, B11, MFMA(af0, B01, zz));
        acc[2] = MFMA(af1, B12, MFMA(af0, B02, zz));
        acc[3] = MFMA(af1, B13, MFMA(af0, B03, zz));

        // ---- D transpose via LDS, packed f16 (half the bytes; b64 writes
        //      from 16 lanes at stride 8 B are bank-conflict-free)
        {
            const int p = quad >> 1;
            if (!(quad & 1)) {
                #pragma unroll
                for (int t = 0; t < 4; ++t) {
                    int2 v;
                    v.x = pk16(acc[t].x, acc[t].y);
                    v.y = pk16(acc[t].z, acc[t].w);
                    *(int2*)(wb + OFF_DV + (p*64 + t*16 + mrow)*8) = v;
                }
            } else {
                #pragma unroll
                for (int t = 0; t < 4; ++t)
                    *(_Float16*)(wb + OFF_DA + (p*64 + t*16 + mrow)*2) =
                        (_Float16)acc[t].x;
            }
        }

        // ---- per-lane (unit k) read both paths' activations (f16), compute h
        const int2 dv0 = *(const int2*)(wb + OFF_DV + lane*8);
        const int2 dv1 = *(const int2*)(wb + OFF_DV + (64 + lane)*8);
        const float awy0 = (float)*(const _Float16*)(wb + OFF_DA + lane*2);
        const float awy1 = (float)*(const _Float16*)(wb + OFF_DA + (64 + lane)*2);
        {
            const fp16x2 lo = __builtin_bit_cast(fp16x2, dv0.x);
            const fp16x2 hi = __builtin_bit_cast(fp16x2, dv0.y);
            const float a0 = (float)lo.x, aW = (float)lo.y;
            const float aY = (float)hi.x, aWW = (float)hi.y;
            const float t2 = ftanh(a0 + b2k);
            const float d2 = 1.0f - t2*t2, dd2 = -2.0f*t2*d2;
            const float q  = dd2 * aW;
            swp[0*72] = (_Float16)t2;
            swp[1*72] = (_Float16)(d2 * aW);
            swp[2*72] = (_Float16)(d2 * aY);
            swp[3*72] = (_Float16)fmaf(q, aW, d2 * aWW);
            swp[4*72] = (_Float16)fmaf(q, aY, d2 * awy0);
        }
        {
            const fp16x2 lo = __builtin_bit_cast(fp16x2, dv1.x);
            const fp16x2 hi = __builtin_bit_cast(fp16x2, dv1.y);
            const float a0 = (float)lo.x, aW = (float)lo.y;
            const float aY = (float)hi.x, aWW = (float)hi.y;
            const float t2 = ftanh(a0 + b2k);
            const float d2 = 1.0f - t2*t2, dd2 = -2.0f*t2*d2;
            const float q  = dd2 * aW;
            swp[8*72]  = (_Float16)t2;
            swp[9*72]  = (_Float16)(d2 * aW);
            swp[10*72] = (_Float16)(d2 * aY);
            swp[11*72] = (_Float16)fmaf(q, aW, d2 * aWW);
            swp[12*72] = (_Float16)fmaf(q, aY, d2 * awy1);
        }

        // ---- layer 3 via MFMA (w3 broadcast over n -> all cols equal)
        half8 bf0 = __builtin_bit_cast(half8, *(const f32x4*)arp0);
        half8 bf1 = __builtin_bit_cast(half8, *(const f32x4*)(arp0 + 64));
        f32x4 acc4 = MFMA(bf1, W31, MFMA(bf0, W30, zz));

        // scatter per-path policy jets (f32 — error-sensitive, cheap: 4 DS ops)
        if (mrow == 0) {
            const int p = quad >> 1;
            if (!(quad & 1)) *(f32x4*)(wb + OFF_PV + p*16) = acc4;
            else             *(float*)(wb + OFF_PA + p*4)  = acc4.x;
        }
        const f32x4 pv  = *(const f32x4*)(wb + OFF_PV + par*16);
        const float pWY = *(const float*)(wb + OFF_PA + par*4);
        const float pi  = pv.x + b3v;
        const float pW  = pv.y, pY = pv.z, pWW = pv.w;

        // ---- dynamics + jet update (refactored: shared GdtSn factor)
        const float Sn    = ksn * z1;
        const float say   = ksa * Yv;
        const float G     = fmaf(-ks2, pi, say);
        const float GdtSn = fmaf(G, C_DT, Sn);

        const float w2v  = W * W;
        const float piL  = pW * W;
        const float piLL = fmaf(pWW, w2v, piL);
        const float piY  = pY;
        const float piLY = pWY * W;

        const float pi2  = pi * pi;
        const float Lnew = fmaf(pi, fmaf(say, C_DT, Sn),
                                fmaf(-kv, pi2, L + kRdt));

        const float F_L  = fmaf(piL, GdtSn, 1.0f);
        const float F_Y  = fmaf(piY, GdtSn, kFy * pi);
        const float piL2 = piL * piL;
        const float F_LL = fmaf(piLL, GdtSn, -(ksd * piL2));
        const float F_LY = fmaf(piLY, GdtSn, piL * fmaf(-ksd, piY, kFy));

        const float gW2  = gW * gW;
        const float hWWn = fmaf(F_LL, gW2, F_L * hWW);
        const float hWYn = fmaf(F_LL, gW * gY,
                                fmaf(F_LY, gW * cYt, F_L * hWY));
        const float gWn  = F_L * gW;
        const float gYn  = fmaf(F_Y, cYt, F_L * gY);

        Yv  = fmaf(ky2, z2, fmaf(ky1, z1, cYfac * Yv));
        cYt *= cYfac;

        const float We   = __expf(Lnew);
        const bool  clip = (We < C_LBW);
        L   = clip ? C_LOGLBW : Lnew;
        W   = clip ? C_LBW    : We;
        gW  = clip ? 0.0f : gWn;
        gY  = clip ? 0.0f : gYn;
        hWW = clip ? 0.0f : hWWn;
        hWY = clip ? 0.0f : hWYn;
        tmt -= C_DT;
    }

    // terminal utility U = -0.25*exp(-4L); direct per-branch store (no atomics)
    const float E   = __expf(-4.0f * L);
    const float d1  = E * gW;
    const float d2v = fmaf(-4.0f * E, gW * gW, E * hWW);
    const float d3v = fmaf(-4.0f * E, gW * gY, E * hWY);

    if (lane < 2) {   // lane 0 = path 2w', lane 1 = path 2w'+1
        const int branch = simb * BTOT + pg;      // 0..8191, branch&31 == i
        sd[         branch] = 0.5f * d1;
        sd[  NSIM + branch] = 0.5f * d2v;
        sd[2*NSIM + branch] = 0.5f * d3v;
    }
}

__global__ void proj_kernel(const float* __restrict__ sd,
                            const float* __restrict__ Wp,
                            const float* __restrict__ Yp,
                            float* __restrict__ out)
{
    const int i = threadIdx.x;
    if (i >= NPTS) return;
    float lam = 0.0f, dW = 0.0f, dY = 0.0f;
    #pragma unroll 8
    for (int j = 0; j < NSIM / NPTS; ++j) {     // 256 entries, stride 32 (coalesced)
        const int idx = i + (j << 5);
        lam += sd[idx];
        dW  += sd[NSIM + idx];
        dY  += sd[2*NSIM + idx];
    }
    lam *= (1.0f / 2097152.0f);     // /128^3
    dW  *= (1.0f / 268435456.0f);   // /128^4
    dY  *= (1.0f / 268435456.0f);
    const float Wv = Wp[i], Yv = Yp[i];
    const float mmr   = C_SIGMA * (C_ALPHA * Yv);
    const float sig2  = C_SIGMA * C_SIGMA;
    const float coeff = -1.0f / (Wv * dW + 1e-8f);
    const float myo   = coeff * (lam * (mmr / sig2));
    const float hedge = coeff * (C_SIGMA * C_RHO * C_SIGY * dY / sig2);
    float v = myo + hedge;
    v = fminf(fmaxf(v, -2.0f), 2.0f);
    out[i] = v;
}

extern "C" void kernel_launch(void* const* d_in, const int* in_sizes, int n_in,
                              void* d_out, int out_size, void* d_ws, size_t ws_size,
                              hipStream_t stream) {
    const float* Wp    = (const float*)d_in[0];
    // d_in[1] = TmT (unused: reference simulates from T_H constant)
    const float* Yp    = (const float*)d_in[2];
    const float* noise = (const float*)d_in[3];
    const float* w1    = (const float*)d_in[4];
    const float* b1    = (const float*)d_in[5];
    const float* w2    = (const float*)d_in[6];
    const float* b2    = (const float*)d_in[7];
    const float* w3    = (const float*)d_in[8];
    const float* b3    = (const float*)d_in[9];
    float* out = (float*)d_out;
    float* sd  = (float*)d_ws;   // 3*8192 floats = 96 KB staging

    hipLaunchKernelGGL(sim_kernel, dim3(NWAVE/4), dim3(256), 0, stream,
                       noise, w1, b1, w2, b2, w3, b3, Wp, Yp, sd);
    hipLaunchKernelGGL(proj_kernel, dim3(1), dim3(64), 0, stream, sd, Wp, Yp, out);
}

// Round 17
// 183.670 us; speedup vs baseline: 1.0610x; 1.0259x over previous
//
#include <hip/hip_runtime.h>
#include <math.h>

#define HID    64
#define MSTEPS 60
#define NPTS   32
#define RPTSC  128
#define BTOT   (RPTSC*NPTS)    // 4096 paths
#define NSIM   (2*BTOT)        // 8192 path-branches
#define NWAVE  (NSIM/2)        // 4096 waves, 2 path-branches per wave

// hard-coded model constants (match reference, fp32 semantics)
#define C_DT     0.025f
#define C_SQDT   0.15811388300841897f   // sqrt(0.025)
#define C_ALPHA  0.8f
#define C_RHO    0.3f
#define C_SQ1MR2 0.9539392014169456f    // sqrt(1-0.09)
#define C_KAPPA  1.2f
#define C_R      0.02f
#define C_SIGMA  0.2f
#define C_SIGY   0.3f
#define C_LBW    1e-3f
#define C_LOGLBW -6.907755279f          // log(1e-3)

// per-wave LDS layout (f16 D-transpose; PV round trip replaced by ds_swizzle):
//   [0,2304)      A-buffer: 16 rows x 144 B (64 f16 + 16 B pad)
//   [2304,3328)   DV: f16x4[2][64]  (a0,aW,aY,aWW per path per unit, 8 B each)
//   [3328,3584)   DA: f16[2][64]    (aWY)
#define WAVE_LDS 3584
#define A_ROW    144
#define OFF_DV   2304
#define OFF_DA   3328

typedef _Float16 half8 __attribute__((ext_vector_type(8)));
typedef float    f32x4 __attribute__((ext_vector_type(4)));
typedef __fp16   fp16x2 __attribute__((ext_vector_type(2)));

__device__ __forceinline__ float rlanef(float v, int l) {
    return __int_as_float(__builtin_amdgcn_readlane(__float_as_int(v), l));
}
// static-pattern lane crossbar within 32-lane groups (BitMode):
// src_lane = ((lane & and) | or) ^ xor ; offset = (xor<<10)|(or<<5)|and
template <int OFF>
__device__ __forceinline__ float swz(float v) {
    return __int_as_float(__builtin_amdgcn_ds_swizzle(__float_as_int(v), OFF));
}
__device__ __forceinline__ f32x4 MFMA(half8 a, half8 b, f32x4 c) {
    return __builtin_amdgcn_mfma_f32_16x16x32_f16(a, b, c, 0, 0, 0);
}
// tanh(x) = 1 - 2/(e^{2x}+1)
__device__ __forceinline__ float ftanh(float x) {
    float e = __expf(2.0f * x);
    return 1.0f - 2.0f * __builtin_amdgcn_rcpf(e + 1.0f);
}
// pack two f32 -> f16x2 (RTZ) as int
__device__ __forceinline__ int pk16(float a, float b) {
    return __builtin_bit_cast(int, __builtin_amdgcn_cvt_pkrtz(a, b));
}

// sim: per-branch derivatives stored directly (no atomics, no zero-init).
// sd[c*NSIM + branch], branch = simb*BTOT + pg; branch & 31 == eval point.
__global__ __launch_bounds__(256, 4) void sim_kernel(
    const float* __restrict__ noise,
    const float* __restrict__ w1, const float* __restrict__ b1,
    const float* __restrict__ w2, const float* __restrict__ b2,
    const float* __restrict__ w3, const float* __restrict__ b3,
    const float* __restrict__ Wp, const float* __restrict__ Yp,
    float* __restrict__ sd)
{
    __shared__ __align__(16) char smem[4 * WAVE_LDS];
    const int lane = threadIdx.x & 63;
    const int quad = lane >> 4;      // 0..3
    const int mrow = lane & 15;      // 0..15
    const int par  = lane >> 5;      // path half: lanes 0-31 path0, 32-63 path1
    char* wb = smem + (threadIdx.x >> 6) * WAVE_LDS;

    const int w = __builtin_amdgcn_readfirstlane(
        (int)((blockIdx.x * blockDim.x + threadIdx.x) >> 6));   // 0..4095
    const int simb = w >> 11;                 // antithetic branch (uniform per wave)
    const int pg   = 2*(w & 2047) + par;      // per-lane global path 0..4095
    const int i    = pg & (NPTS - 1);         // per-lane eval point

    // per-lane layer-1 weights (lane = hidden unit)
    const float cW  = w1[lane];
    const float cT  = w1[HID + lane];
    const float cYw = w1[2*HID + lane];
    const float b1k = b1[lane];
    const float b2k = b2[lane];
    const float b3v = b3[0];
    const float cW2  = cW * cW;
    const float cWYc = cW * cYw;

    // MFMA B fragments (f16): B[k][n], n=mrow+t*16, k=q*32+quad*8+j
    half8 B00, B01, B02, B03, B10, B11, B12, B13, W30, W31;
    {
        half8 h;
        #define LOADB(dst, q, t) \
            { for (int j = 0; j < 8; ++j) \
                h[j] = (_Float16)w2[((q)*32 + quad*8 + j)*HID + (t)*16 + mrow]; \
              dst = h; }
        LOADB(B00, 0, 0) LOADB(B01, 0, 1) LOADB(B02, 0, 2) LOADB(B03, 0, 3)
        LOADB(B10, 1, 0) LOADB(B11, 1, 1) LOADB(B12, 1, 2) LOADB(B13, 1, 3)
        #undef LOADB
        for (int j = 0; j < 8; ++j) h[j] = (_Float16)w3[0*32 + quad*8 + j];
        W30 = h;
        for (int j = 0; j < 8; ++j) h[j] = (_Float16)w3[1*32 + quad*8 + j];
        W31 = h;
    }

    // zero A-buffer once (rows 5-7, 13-15 must stay zero)
    for (int off = lane*4; off < 16*A_ROW; off += 256)
        *(float*)(wb + off) = 0.0f;

    // LDS addresses
    _Float16* swp = (_Float16*)(wb + lane*2);   // + row*72 elements
    char* arp0 = wb + mrow*A_ROW + quad*16;     // A-frag k-iter 0 (+64 B for iter 1)

    // per-lane noise pointers (half-wave uniform)
    const float* zp1 = noise + (size_t)(simb*2 + 0) * MSTEPS * BTOT + pg;
    const float* zp2 = noise + (size_t)(simb*2 + 1) * MSTEPS * BTOT + pg;

    // ---- precomputed dynamics coefficients (fold anti & constants)
    const float anti = simb ? -1.0f : 1.0f;
    const float ksa  = C_SIGMA * C_ALPHA;
    const float ks2  = C_SIGMA * C_SIGMA;
    const float ksn  = anti * C_SIGMA * C_SQDT;
    const float kFy  = ksa * C_DT;
    const float ksd  = ks2 * C_DT;
    const float kv   = 0.5f * ks2 * C_DT;
    const float kRdt = C_R * C_DT;
    const float ky1  = anti * C_SIGY * C_SQDT * C_RHO;
    const float ky2  = anti * C_SIGY * C_SQDT * C_SQ1MR2;
    const float cYfac = 1.0f - C_KAPPA * C_DT;

    // per-lane path state + jets of L = logW
    const float W0 = Wp[i];
    float L   = __logf(fmaxf(W0, C_LBW));
    float W   = __expf(L);
    float Yv  = Yp[i];
    float tmt = 1.5f;
    float gW  = 1.0f / W0;
    float hWW = -gW * gW;
    float gY  = 0.0f, hWY = 0.0f;
    float cYt = 1.0f;

    #pragma unroll 1
    for (int m = 0; m < MSTEPS; ++m) {
        asm volatile("" : "+v"(B00), "+v"(B01), "+v"(B02), "+v"(B03),
                          "+v"(B10), "+v"(B11), "+v"(B12), "+v"(B13),
                          "+v"(W30), "+v"(W31));

        const float z1 = zp1[(size_t)m * BTOT];
        const float z2 = zp2[(size_t)m * BTOT];

        // broadcast both paths' (W,Y): path0 state in lane 0, path1 in lane 32
        const float Wb0 = rlanef(W, 0),  Wb1 = rlanef(W, 32);
        const float Yb0 = rlanef(Yv, 0), Yb1 = rlanef(Yv, 32);

        // ---- layer 1 + tanh for both paths; marshal A rows 8p..8p+4
        const float base1 = fmaf(tmt, cT, b1k);
        {
            const float t1 = ftanh(fmaf(Wb0, cW, fmaf(Yb0, cYw, base1)));
            const float dp = 1.0f - t1*t1, ddp = -2.0f*t1*dp;
            swp[0*72] = (_Float16)t1;
            swp[1*72] = (_Float16)(dp * cW);
            swp[2*72] = (_Float16)(dp * cYw);
            swp[3*72] = (_Float16)(ddp * cW2);
            swp[4*72] = (_Float16)(ddp * cWYc);
        }
        {
            const float t1 = ftanh(fmaf(Wb1, cW, fmaf(Yb1, cYw, base1)));
            const float dp = 1.0f - t1*t1, ddp = -2.0f*t1*dp;
            swp[8*72]  = (_Float16)t1;
            swp[9*72]  = (_Float16)(dp * cW);
            swp[10*72] = (_Float16)(dp * cYw);
            swp[11*72] = (_Float16)(ddp * cW2);
            swp[12*72] = (_Float16)(ddp * cWYc);
        }

        half8 af0 = __builtin_bit_cast(half8, *(const f32x4*)arp0);
        half8 af1 = __builtin_bit_cast(half8, *(const f32x4*)(arp0 + 64));

        // ---- layer 2 GEMM: 4 N-tiles x 2 K-iters
        f32x4 acc[4];
        const f32x4 zz = {0.f, 0.f, 0.f, 0.f};
        acc[0] = MFMA(af1, B10, MFMA(af0, B00, zz));
        acc[1] = MFMA(af1, B11, MFMA(af0, B01, zz));
        acc[2] = MFMA(af1, B12, MFMA(af0, B02, zz));
        acc[3] = MFMA(af1, B13, MFMA(af0, B03, zz));

        // ---- D transpose via LDS, packed f16 (R16)
        {
            const int p = quad >> 1;
            if (!(quad & 1)) {
                #pragma unroll
                for (int t = 0; t < 4; ++t) {
                    int2 v;
                    v.x = pk16(acc[t].x, acc[t].y);
                    v.y = pk16(acc[t].z, acc[t].w);
                    *(int2*)(wb + OFF_DV + (p*64 + t*16 + mrow)*8) = v;
                }
            } else {
                #pragma unroll
                for (int t = 0; t < 4; ++t)
                    *(_Float16*)(wb + OFF_DA + (p*64 + t*16 + mrow)*2) =
                        (_Float16)acc[t].x;
            }
        }

        // ---- per-lane (unit k) read both paths' activations (f16), compute h
        const int2 dv0 = *(const int2*)(wb + OFF_DV + lane*8);
        const int2 dv1 = *(const int2*)(wb + OFF_DV + (64 + lane)*8);
        const float awy0 = (float)*(const _Float16*)(wb + OFF_DA + lane*2);
        const float awy1 = (float)*(const _Float16*)(wb + OFF_DA + (64 + lane)*2);
        {
            const fp16x2 lo = __builtin_bit_cast(fp16x2, dv0.x);
            const fp16x2 hi = __builtin_bit_cast(fp16x2, dv0.y);
            const float a0 = (float)lo.x, aW = (float)lo.y;
            const float aY = (float)hi.x, aWW = (float)hi.y;
            const float t2 = ftanh(a0 + b2k);
            const float d2 = 1.0f - t2*t2, dd2 = -2.0f*t2*d2;
            const float q  = dd2 * aW;
            swp[0*72] = (_Float16)t2;
            swp[1*72] = (_Float16)(d2 * aW);
            swp[2*72] = (_Float16)(d2 * aY);
            swp[3*72] = (_Float16)fmaf(q, aW, d2 * aWW);
            swp[4*72] = (_Float16)fmaf(q, aY, d2 * awy0);
        }
        {
            const fp16x2 lo = __builtin_bit_cast(fp16x2, dv1.x);
            const fp16x2 hi = __builtin_bit_cast(fp16x2, dv1.y);
            const float a0 = (float)lo.x, aW = (float)lo.y;
            const float aY = (float)hi.x, aWW = (float)hi.y;
            const float t2 = ftanh(a0 + b2k);
            const float d2 = 1.0f - t2*t2, dd2 = -2.0f*t2*d2;
            const float q  = dd2 * aW;
            swp[8*72]  = (_Float16)t2;
            swp[9*72]  = (_Float16)(d2 * aW);
            swp[10*72] = (_Float16)(d2 * aY);
            swp[11*72] = (_Float16)fmaf(q, aW, d2 * aWW);
            swp[12*72] = (_Float16)fmaf(q, aY, d2 * awy1);
        }

        // ---- layer 3 via MFMA (w3 broadcast over n -> all cols equal)
        half8 bf0 = __builtin_bit_cast(half8, *(const f32x4*)arp0);
        half8 bf1 = __builtin_bit_cast(half8, *(const f32x4*)(arp0 + 64));
        f32x4 acc4 = MFMA(bf1, W31, MFMA(bf0, W30, zz));

        // ---- policy-jet broadcast via ds_swizzle (static crossbar, 32-lane
        // groups — no LDS memory round trip, no bank conflicts):
        // rows 8p..8p+3 live in lane 32p regs x..w -> offset 0x0000 (group lane 0)
        // row 8p+4 lives in lane 32p+16 reg x      -> offset 0x0200 (group lane 16)
        const float pi  = swz<0x0000>(acc4.x) + b3v;
        const float pW  = swz<0x0000>(acc4.y);
        const float pY  = swz<0x0000>(acc4.z);
        const float pWW = swz<0x0000>(acc4.w);
        const float pWY = swz<0x0200>(acc4.x);

        // ---- dynamics + jet update (refactored: shared GdtSn factor)
        const float Sn    = ksn * z1;
        const float say   = ksa * Yv;
        const float G     = fmaf(-ks2, pi, say);
        const float GdtSn = fmaf(G, C_DT, Sn);

        const float w2v  = W * W;
        const float piL  = pW * W;
        const float piLL = fmaf(pWW, w2v, piL);
        const float piY  = pY;
        const float piLY = pWY * W;

        const float pi2  = pi * pi;
        const float Lnew = fmaf(pi, fmaf(say, C_DT, Sn),
                                fmaf(-kv, pi2, L + kRdt));

        const float F_L  = fmaf(piL, GdtSn, 1.0f);
        const float F_Y  = fmaf(piY, GdtSn, kFy * pi);
        const float piL2 = piL * piL;
        const float F_LL = fmaf(piLL, GdtSn, -(ksd * piL2));
        const float F_LY = fmaf(piLY, GdtSn, piL * fmaf(-ksd, piY, kFy));

        const float gW2  = gW * gW;
        const float hWWn = fmaf(F_LL, gW2, F_L * hWW);
        const float hWYn = fmaf(F_LL, gW * gY,
                                fmaf(F_LY, gW * cYt, F_L * hWY));
        const float gWn  = F_L * gW;
        const float gYn  = fmaf(F_Y, cYt, F_L * gY);

        Yv  = fmaf(ky2, z2, fmaf(ky1, z1, cYfac * Yv));
        cYt *= cYfac;

        const float We   = __expf(Lnew);
        const bool  clip = (We < C_LBW);
        L   = clip ? C_LOGLBW : Lnew;
        W   = clip ? C_LBW    : We;
        gW  = clip ? 0.0f : gWn;
        gY  = clip ? 0.0f : gYn;
        hWW = clip ? 0.0f : hWWn;
        hWY = clip ? 0.0f : hWYn;
        tmt -= C_DT;
    }

    // terminal utility U = -0.25*exp(-4L); direct per-branch store (no atomics)
    const float E   = __expf(-4.0f * L);
    const float d1  = E * gW;
    const float d2v = fmaf(-4.0f * E, gW * gW, E * hWW);
    const float d3v = fmaf(-4.0f * E, gW * gY, E * hWY);

    if ((lane & 31) == 0) {   // lane 0 = path 2w', lane 32 = path 2w'+1
        const int branch = simb * BTOT + pg;      // 0..8191, branch&31 == i
        sd[         branch] = 0.5f * d1;
        sd[  NSIM + branch] = 0.5f * d2v;
        sd[2*NSIM + branch] = 0.5f * d3v;
    }
}

__global__ void proj_kernel(const float* __restrict__ sd,
                            const float* __restrict__ Wp,
                            const float* __restrict__ Yp,
                            float* __restrict__ out)
{
    const int i = threadIdx.x;
    if (i >= NPTS) return;
    float lam = 0.0f, dW = 0.0f, dY = 0.0f;
    #pragma unroll 8
    for (int j = 0; j < NSIM / NPTS; ++j) {     // 256 entries, stride 32 (coalesced)
        const int idx = i + (j << 5);
        lam += sd[idx];
        dW  += sd[NSIM + idx];
        dY  += sd[2*NSIM + idx];
    }
    lam *= (1.0f / 2097152.0f);     // /128^3
    dW  *= (1.0f / 268435456.0f);   // /128^4
    dY  *= (1.0f / 268435456.0f);
    const float Wv = Wp[i], Yv = Yp[i];
    const float mmr   = C_SIGMA * (C_ALPHA * Yv);
    const float sig2  = C_SIGMA * C_SIGMA;
    const float coeff = -1.0f / (Wv * dW + 1e-8f);
    const float myo   = coeff * (lam * (mmr / sig2));
    const float hedge = coeff * (C_SIGMA * C_RHO * C_SIGY * dY / sig2);
    float v = myo + hedge;
    v = fminf(fmaxf(v, -2.0f), 2.0f);
    out[i] = v;
}

extern "C" void kernel_launch(void* const* d_in, const int* in_sizes, int n_in,
                              void* d_out, int out_size, void* d_ws, size_t ws_size,
                              hipStream_t stream) {
    const float* Wp    = (const float*)d_in[0];
    // d_in[1] = TmT (unused: reference simulates from T_H constant)
    const float* Yp    = (const float*)d_in[2];
    const float* noise = (const float*)d_in[3];
    const float* w1    = (const float*)d_in[4];
    const float* b1    = (const float*)d_in[5];
    const float* w2    = (const float*)d_in[6];
    const float* b2    = (const float*)d_in[7];
    const float* w3    = (const float*)d_in[8];
    const float* b3    = (const float*)d_in[9];
    float* out = (float*)d_out;
    float* sd  = (float*)d_ws;   // 3*8192 floats = 96 KB staging

    hipLaunchKernelGGL(sim_kernel, dim3(NWAVE/4), dim3(256), 0, stream,
                       noise, w1, b1, w2, b2, w3, b3, Wp, Yp, sd);
    hipLaunchKernelGGL(proj_kernel, dim3(1), dim3(64), 0, stream, sd, Wp, Yp, out);
}